// Round 3
// baseline (325.022 us; speedup 1.0000x reference)
//
#include <hip/hip_runtime.h>

// Problem constants: B=8, N=1024, C=64, O=64, K+1=4
#define EPS_Q 1e-12f

// Native clang vector for __builtin_nontemporal_load (HIP_vector_type is
// rejected by the builtin's type checker).
typedef float nfloat4 __attribute__((ext_vector_type(4)));

__device__ __forceinline__ float wave_reduce_sum(float v) {
#pragma unroll
    for (int m = 32; m > 0; m >>= 1) v += __shfl_xor(v, m, 64);
    return v;
}

// ---------------------------------------------------------------------------
// Kernel A (R10): scores + U/V recombination panels, fused.
// 512 blocks x 16 rows. X rows staged once in LDS; weights read ONCE per
// block (128 KB -> 64 MB aggregate L2 traffic, 4x less than per-wave).
//   scores: sRi/sIi/sRj/sIj per row (SoA), same math as before.
//   panels: U[row][o].m = sum_c Xr[row,c]*wr[m,c,o]  (V from Xi*wi),
//           stored as float4 with component=m -> 16B/lane coalesced.
// ---------------------------------------------------------------------------
__global__ __launch_bounds__(256)
void k_scores_uv(const float* __restrict__ Xr, const float* __restrict__ Xi,
                 const float* __restrict__ awr, const float* __restrict__ awi,
                 const float* __restrict__ wr, const float* __restrict__ wi,
                 float* __restrict__ sRi, float* __restrict__ sIi,
                 float* __restrict__ sRj, float* __restrict__ sIj,
                 float4* __restrict__ U4, float4* __restrict__ V4) {
    __shared__ float lxr[16][64];
    __shared__ float lxi[16][64];
    const int tid = threadIdx.x;
    const int rb  = blockIdx.x << 4;  // 16 rows per block
    {
        const float4* s0 = (const float4*)(Xr + (size_t)rb * 64);
        const float4* s1 = (const float4*)(Xi + (size_t)rb * 64);
        ((float4*)&lxr[0][0])[tid] = s0[tid];  // 16*64 floats = 256 float4
        ((float4*)&lxi[0][0])[tid] = s1[tid];
    }
    __syncthreads();
    const int wave = tid >> 6, lane = tid & 63;
    const int r0 = wave << 2;  // 4 rows per wave

    // ---- scores for this wave's 4 rows (lane = c) ----
    {
        const float wri = awr[lane], wrj = awr[64 + lane];
        const float wii = awi[lane], wij = awi[64 + lane];
#pragma unroll
        for (int r = 0; r < 4; ++r) {
            const int row = rb + r0 + r;
            const float xr = lxr[r0 + r][lane];
            const float xi = lxi[r0 + r][lane];
            float v0 = xr * wri - xi * wii;   // sR_i partial
            float v1 = xr * wii + xi * wri;   // sI_i partial
            float v2 = xr * wrj - xi * wij;   // sR_j partial
            float v3 = xr * wij + xi * wrj;   // sI_j partial
#pragma unroll
            for (int m = 32; m > 0; m >>= 1) {
                v0 += __shfl_xor(v0, m, 64);
                v1 += __shfl_xor(v1, m, 64);
                v2 += __shfl_xor(v2, m, 64);
                v3 += __shfl_xor(v3, m, 64);
            }
            if (lane == 0) {
                sRi[row] = v0;
                sIi[row] = v1;
                sRj[row] = v2;
                sIj[row] = v3;
            }
        }
    }

    // ---- U/V panels (lane = o), identical accumulation order to old k_output ----
    float u[4][4], v[4][4];
#pragma unroll
    for (int r = 0; r < 4; ++r)
#pragma unroll
        for (int m = 0; m < 4; ++m) { u[r][m] = 0.f; v[r][m] = 0.f; }
    for (int c = 0; c < 64; ++c) {
        float wrv[4], wiv[4];
#pragma unroll
        for (int m = 0; m < 4; ++m) {
            wrv[m] = wr[((m << 6) + c) * 64 + lane];
            wiv[m] = wi[((m << 6) + c) * 64 + lane];
        }
#pragma unroll
        for (int r = 0; r < 4; ++r) {
            const float xr = lxr[r0 + r][c];
            const float xi = lxi[r0 + r][c];
#pragma unroll
            for (int m = 0; m < 4; ++m) {
                u[r][m] += xr * wrv[m];
                v[r][m] += xi * wiv[m];
            }
        }
    }
#pragma unroll
    for (int r = 0; r < 4; ++r) {
        const int row = rb + r0 + r;
        U4[(row << 6) + lane] = make_float4(u[r][0], u[r][1], u[r][2], u[r][3]);
        V4[(row << 6) + lane] = make_float4(v[r][0], v[r][1], v[r][2], v[r][3]);
    }
}

// ---------------------------------------------------------------------------
// Kernel B: column softmax stats over axis i for each (b, j). One wave per
// (b, j). Writes cmax = colmax, cinv = 1/sum(exp(mag-colmax)) (SoA).
// ---------------------------------------------------------------------------
__global__ __launch_bounds__(256)
void k_softmax(const float* __restrict__ sRi, const float* __restrict__ sIi,
               const float* __restrict__ sRj, const float* __restrict__ sIj,
               float* __restrict__ cmax, float* __restrict__ cinv,
               const float* __restrict__ abr, const float* __restrict__ abi,
               const float* __restrict__ par_, const float* __restrict__ pai_) {
    const int lane = threadIdx.x & 63;
    const int row  = (blockIdx.x << 2) + (threadIdx.x >> 6);  // b*N + j
    const int b    = row >> 10;
    const float br = abr[0], bi = abi[0], par = par_[0], pai = pai_[0];
    const float sRjv = sRj[row], sIjv = sIj[row];
    const float* pR = sRi + (b << 10);
    const float* pI = sIi + (b << 10);
    float mags[16];
    float mx = -3.4e38f;
#pragma unroll
    for (int t = 0; t < 16; ++t) {
        const int i = (t << 6) + lane;
        float sr = pR[i] + sRjv + br;
        float si = pI[i] + sIjv + bi;
        float pr = sr >= 0.f ? sr : par * sr;
        float pi = si >= 0.f ? si : pai * si;
        float mg = sqrtf(pr * pr + pi * pi);
        mags[t] = mg;
        mx = fmaxf(mx, mg);
    }
#pragma unroll
    for (int m = 32; m > 0; m >>= 1) mx = fmaxf(mx, __shfl_xor(mx, m, 64));
    float s = 0.f;
#pragma unroll
    for (int t = 0; t < 16; ++t) s += __expf(mags[t] - mx);
    s = wave_reduce_sum(s);
    if (lane == 0) {
        cmax[row] = mx;
        cinv[row] = 1.f / s;
    }
}

// ---------------------------------------------------------------------------
// Helper: attention coefficient for one (i,j) from SoA stats.
// ---------------------------------------------------------------------------
__device__ __forceinline__ void attn_coef(float srj, float sij, float mx, float is,
                                          float sri, float sii,
                                          float br, float bi, float par, float pai,
                                          float& ar, float& ai) {
    float sr = sri + srj + br;
    float si = sii + sij + bi;
    float pr = sr >= 0.f ? sr : par * sr;
    float pi = si >= 0.f ? si : pai * si;
    float mg = sqrtf(pr * pr + pi * pi);
    float sc = __expf(mg - mx) * is / (mg + EPS_Q);
    ar = sc * pr;
    ai = sc * pi;
}

#define FMA_BURST(m, R, Q)                                              \
    {                                                                   \
        _Pragma("unroll")                                               \
        for (int t = 0; t < 4; ++t) {                                   \
            accR[m] += R[t].x * arv[(t << 2) + 0] - Q[t].x * aiv[(t << 2) + 0]; \
            accI[m] += R[t].x * aiv[(t << 2) + 0] + Q[t].x * arv[(t << 2) + 0]; \
            accR[m] += R[t].y * arv[(t << 2) + 1] - Q[t].y * aiv[(t << 2) + 1]; \
            accI[m] += R[t].y * aiv[(t << 2) + 1] + Q[t].y * arv[(t << 2) + 1]; \
            accR[m] += R[t].z * arv[(t << 2) + 2] - Q[t].z * aiv[(t << 2) + 2]; \
            accI[m] += R[t].z * aiv[(t << 2) + 2] + Q[t].z * arv[(t << 2) + 2]; \
            accR[m] += R[t].w * arv[(t << 2) + 3] - Q[t].w * aiv[(t << 2) + 3]; \
            accI[m] += R[t].w * aiv[(t << 2) + 3] + Q[t].w * arv[(t << 2) + 3]; \
        }                                                               \
    }

#define LOAD_BURST(m, R, Q)                                             \
    {                                                                   \
        _Pragma("unroll")                                               \
        for (int t = 0; t < 4; ++t) {                                   \
            R[t] = __builtin_nontemporal_load(&LR[((m) << 18) + (t << 6) + lane]); \
            Q[t] = __builtin_nontemporal_load(&LI[((m) << 18) + (t << 6) + lane]); \
        }                                                               \
    }

// ---------------------------------------------------------------------------
// Kernel C (R10): pure stream + trivial tail. One wave per (b,i).
//  - First HBM burst issued BEFORE the coefficient prelude, so the ~700 cy of
//    exp/sqrt/rcp VALU hides under first-burst latency and read traffic
//    starts at cycle ~0 of the kernel.
//  - 2-deep burst pipeline over the 4 m-slices (A/B buffer sets).
//  - Tail: butterfly (all lanes get rowR/rowI[m]) with the 1 KB U/V panel
//    loads pre-issued under it, then 16 complex FMAs and the out store.
//    No LDS, no __syncthreads, no weight reads, no shuffle-GEMM.
// ---------------------------------------------------------------------------
__global__ __launch_bounds__(256)
void k_stream(const float* __restrict__ Lr, const float* __restrict__ Li,
              const float* __restrict__ sRi, const float* __restrict__ sIi,
              const float* __restrict__ sRj, const float* __restrict__ sIj,
              const float* __restrict__ cmax, const float* __restrict__ cinv,
              const float* __restrict__ abr, const float* __restrict__ abi,
              const float* __restrict__ par_, const float* __restrict__ pai_,
              const float4* __restrict__ U4, const float4* __restrict__ V4,
              float* __restrict__ out) {
    const int lane = threadIdx.x & 63;
    const int wave = threadIdx.x >> 6;
    const int wid  = (blockIdx.x << 2) + wave;  // b*N + i
    const int b    = wid >> 10;
    const int i    = wid & 1023;

    // Stream bases; float4-index stride per m-slice = 1<<18.
    const size_t base = ((size_t)b << 22) + ((size_t)i << 10);
    const nfloat4* LR = (const nfloat4*)(Lr + base);
    const nfloat4* LI = (const nfloat4*)(Li + base);

    nfloat4 rA[4], qA[4], rB[4], qB[4];
    LOAD_BURST(0, rA, qA);            // HBM traffic in flight from cycle ~0

    // Prelude (hides under burst-0 latency): 16 ar/ai pairs per lane.
    const float br = abr[0], bi = abi[0], par = par_[0], pai = pai_[0];
    const float sri = sRi[wid], sii = sIi[wid];
    const float4* SRJ = (const float4*)(sRj + (b << 10));
    const float4* SIJ = (const float4*)(sIj + (b << 10));
    const float4* CMX = (const float4*)(cmax + (b << 10));
    const float4* CIV = (const float4*)(cinv + (b << 10));
    float arv[16], aiv[16];
#pragma unroll
    for (int t = 0; t < 4; ++t) {
        const int j4 = (t << 6) + lane;
        const float4 vr = SRJ[j4];
        const float4 vi = SIJ[j4];
        const float4 vm = CMX[j4];
        const float4 vs = CIV[j4];
        attn_coef(vr.x, vi.x, vm.x, vs.x, sri, sii, br, bi, par, pai,
                  arv[(t << 2) + 0], aiv[(t << 2) + 0]);
        attn_coef(vr.y, vi.y, vm.y, vs.y, sri, sii, br, bi, par, pai,
                  arv[(t << 2) + 1], aiv[(t << 2) + 1]);
        attn_coef(vr.z, vi.z, vm.z, vs.z, sri, sii, br, bi, par, pai,
                  arv[(t << 2) + 2], aiv[(t << 2) + 2]);
        attn_coef(vr.w, vi.w, vm.w, vs.w, sri, sii, br, bi, par, pai,
                  arv[(t << 2) + 3], aiv[(t << 2) + 3]);
    }

    float accR[4] = {0.f, 0.f, 0.f, 0.f};
    float accI[4] = {0.f, 0.f, 0.f, 0.f};
    LOAD_BURST(1, rB, qB);            // 2 bursts in flight
    FMA_BURST(0, rA, qA);             // consume m0
    LOAD_BURST(2, rA, qA);
    FMA_BURST(1, rB, qB);             // consume m1
    LOAD_BURST(3, rB, qB);
    FMA_BURST(2, rA, qA);             // consume m2
    // Pre-issue the tiny tail loads so they complete under the butterfly.
    const float4 uR = U4[(wid << 6) + lane];
    const float4 vI = V4[(wid << 6) + lane];
    FMA_BURST(3, rB, qB);             // consume m3

    // Butterfly: ALL lanes end up holding the full row sums rowR/rowI[m].
#pragma unroll
    for (int m = 0; m < 4; ++m) {
#pragma unroll
        for (int s = 32; s > 0; s >>= 1) {
            accR[m] += __shfl_xor(accR[m], s, 64);
            accI[m] += __shfl_xor(accI[m], s, 64);
        }
    }

    // Tail: out[b,i,o] = sum_m rowR[m]*u[m] - rowI[m]*v[m]  (and imag).
    float re = 0.f, im = 0.f;
    re += accR[0] * uR.x - accI[0] * vI.x;  im += accI[0] * uR.x + accR[0] * vI.x;
    re += accR[1] * uR.y - accI[1] * vI.y;  im += accI[1] * uR.y + accR[1] * vI.y;
    re += accR[2] * uR.z - accI[2] * vI.z;  im += accI[2] * uR.z + accR[2] * vI.z;
    re += accR[3] * uR.w - accI[3] * vI.w;  im += accI[3] * uR.w + accR[3] * vI.w;
    out[(size_t)wid * 64 + lane] = re;
    out[524288 + (size_t)wid * 64 + lane] = im;  // imag block
}

extern "C" void kernel_launch(void* const* d_in, const int* in_sizes, int n_in,
                              void* d_out, int out_size, void* d_ws, size_t ws_size,
                              hipStream_t stream) {
    const float* Xr  = (const float*)d_in[0];
    const float* Xi  = (const float*)d_in[1];
    const float* Lr  = (const float*)d_in[2];
    const float* Li  = (const float*)d_in[3];
    const float* wr  = (const float*)d_in[4];
    const float* wi  = (const float*)d_in[5];
    const float* awr = (const float*)d_in[6];
    const float* awi = (const float*)d_in[7];
    const float* abr = (const float*)d_in[8];
    const float* abi = (const float*)d_in[9];
    const float* par = (const float*)d_in[10];
    const float* pai = (const float*)d_in[11];
    float* out = (float*)d_out;

    // Workspace layout (floats):
    // sRi[8192] sIi[8192] sRj[8192] sIj[8192] cmax[8192] cinv[8192]  (192 KB)
    // U4[2M floats] V4[2M floats]                                     (16 MB)
    float*  ws   = (float*)d_ws;
    float*  sRi  = ws;
    float*  sIi  = ws + 8192;
    float*  sRj  = ws + 16384;
    float*  sIj  = ws + 24576;
    float*  cmax = ws + 32768;
    float*  cinv = ws + 40960;
    float4* U4   = (float4*)(ws + 49152);
    float4* V4   = (float4*)(ws + 49152 + 2097152);

    k_scores_uv<<<dim3(512),  dim3(256), 0, stream>>>(Xr, Xi, awr, awi, wr, wi,
                                                      sRi, sIi, sRj, sIj, U4, V4);
    k_softmax  <<<dim3(2048), dim3(256), 0, stream>>>(sRi, sIi, sRj, sIj, cmax, cinv,
                                                      abr, abi, par, pai);
    k_stream   <<<dim3(2048), dim3(256), 0, stream>>>(Lr, Li, sRi, sIi, sRj, sIj, cmax, cinv,
                                                      abr, abi, par, pai, U4, V4, out);
}

// Round 5
// 302.370 us; speedup vs baseline: 1.0749x; 1.0749x over previous
//
#include <hip/hip_runtime.h>

// Problem constants: B=8, N=1024, C=64, O=64, K+1=4
#define EPS_Q 1e-12f

// Native clang vector for __builtin_nontemporal_load (HIP_vector_type is
// rejected by the builtin's type checker).
typedef float nfloat4 __attribute__((ext_vector_type(4)));

__device__ __forceinline__ float wave_reduce_sum(float v) {
#pragma unroll
    for (int m = 32; m > 0; m >>= 1) v += __shfl_xor(v, m, 64);
    return v;
}

// ---------------------------------------------------------------------------
// Kernel A: per-node attention scores. One wave per row (b*N+n), lane = c.
// Outputs SoA: sRi/sIi (row term), sRj/sIj (col term) so that the streaming
// kernel's register prelude loads are float4-coalesced.
// ---------------------------------------------------------------------------
__global__ __launch_bounds__(256)
void k_scores(const float* __restrict__ Xr, const float* __restrict__ Xi,
              const float* __restrict__ awr, const float* __restrict__ awi,
              float* __restrict__ sRi, float* __restrict__ sIi,
              float* __restrict__ sRj, float* __restrict__ sIj) {
    const int lane = threadIdx.x & 63;
    const int row  = (blockIdx.x << 2) + (threadIdx.x >> 6);  // b*N + n
    const float xr = Xr[row * 64 + lane];
    const float xi = Xi[row * 64 + lane];
    const float wri = awr[lane], wrj = awr[64 + lane];
    const float wii = awi[lane], wij = awi[64 + lane];
    float v0 = xr * wri - xi * wii;   // sR_i partial
    float v1 = xr * wii + xi * wri;   // sI_i partial
    float v2 = xr * wrj - xi * wij;   // sR_j partial
    float v3 = xr * wij + xi * wrj;   // sI_j partial
#pragma unroll
    for (int m = 32; m > 0; m >>= 1) {
        v0 += __shfl_xor(v0, m, 64);
        v1 += __shfl_xor(v1, m, 64);
        v2 += __shfl_xor(v2, m, 64);
        v3 += __shfl_xor(v3, m, 64);
    }
    if (lane == 0) {
        sRi[row] = v0;
        sIi[row] = v1;
        sRj[row] = v2;
        sIj[row] = v3;
    }
}

// ---------------------------------------------------------------------------
// Kernel B: column softmax stats over axis i for each (b, j). One wave per
// (b, j). Writes cmax = colmax, cinv = 1/sum(exp(mag-colmax)) (SoA).
// ---------------------------------------------------------------------------
__global__ __launch_bounds__(256)
void k_softmax(const float* __restrict__ sRi, const float* __restrict__ sIi,
               const float* __restrict__ sRj, const float* __restrict__ sIj,
               float* __restrict__ cmax, float* __restrict__ cinv,
               const float* __restrict__ abr, const float* __restrict__ abi,
               const float* __restrict__ par_, const float* __restrict__ pai_) {
    const int lane = threadIdx.x & 63;
    const int row  = (blockIdx.x << 2) + (threadIdx.x >> 6);  // b*N + j
    const int b    = row >> 10;
    const float br = abr[0], bi = abi[0], par = par_[0], pai = pai_[0];
    const float sRjv = sRj[row], sIjv = sIj[row];
    const float* pR = sRi + (b << 10);
    const float* pI = sIi + (b << 10);
    float mags[16];
    float mx = -3.4e38f;
#pragma unroll
    for (int t = 0; t < 16; ++t) {
        const int i = (t << 6) + lane;
        float sr = pR[i] + sRjv + br;
        float si = pI[i] + sIjv + bi;
        float pr = sr >= 0.f ? sr : par * sr;
        float pi = si >= 0.f ? si : pai * si;
        float mg = sqrtf(pr * pr + pi * pi);
        mags[t] = mg;
        mx = fmaxf(mx, mg);
    }
#pragma unroll
    for (int m = 32; m > 0; m >>= 1) mx = fmaxf(mx, __shfl_xor(mx, m, 64));
    float s = 0.f;
#pragma unroll
    for (int t = 0; t < 16; ++t) s += __expf(mags[t] - mx);
    s = wave_reduce_sum(s);
    if (lane == 0) {
        cmax[row] = mx;
        cinv[row] = 1.f / s;
    }
}

// ---------------------------------------------------------------------------
// Helper: attention coefficient for one (i,j) from SoA stats.
// ---------------------------------------------------------------------------
__device__ __forceinline__ void attn_coef(float srj, float sij, float mx, float is,
                                          float sri, float sii,
                                          float br, float bi, float par, float pai,
                                          float& ar, float& ai) {
    float sr = sri + srj + br;
    float si = sii + sij + bi;
    float pr = sr >= 0.f ? sr : par * sr;
    float pi = si >= 0.f ? si : pai * si;
    float mg = sqrtf(pr * pr + pi * pi);
    float sc = __expf(mg - mx) * is / (mg + EPS_Q);
    ar = sc * pr;
    ai = sc * pi;
}

#define FMA_BURST(m, R, Q)                                              \
    {                                                                   \
        _Pragma("unroll")                                               \
        for (int t = 0; t < 4; ++t) {                                   \
            accR[m] += R[t].x * arv[(t << 2) + 0] - Q[t].x * aiv[(t << 2) + 0]; \
            accI[m] += R[t].x * aiv[(t << 2) + 0] + Q[t].x * arv[(t << 2) + 0]; \
            accR[m] += R[t].y * arv[(t << 2) + 1] - Q[t].y * aiv[(t << 2) + 1]; \
            accI[m] += R[t].y * aiv[(t << 2) + 1] + Q[t].y * arv[(t << 2) + 1]; \
            accR[m] += R[t].z * arv[(t << 2) + 2] - Q[t].z * aiv[(t << 2) + 2]; \
            accI[m] += R[t].z * aiv[(t << 2) + 2] + Q[t].z * arv[(t << 2) + 2]; \
            accR[m] += R[t].w * arv[(t << 2) + 3] - Q[t].w * aiv[(t << 2) + 3]; \
            accI[m] += R[t].w * aiv[(t << 2) + 3] + Q[t].w * arv[(t << 2) + 3]; \
        }                                                               \
    }

#define LOAD_BURST(m, R, Q)                                             \
    {                                                                   \
        _Pragma("unroll")                                               \
        for (int t = 0; t < 4; ++t) {                                   \
            R[t] = __builtin_nontemporal_load(&LR[((m) << 18) + (t << 6) + lane]); \
            Q[t] = __builtin_nontemporal_load(&LI[((m) << 18) + (t << 6) + lane]); \
        }                                                               \
    }

// ---------------------------------------------------------------------------
// Kernel C (R11 = R9 + LDS-broadcast tail): streaming row-reduce FUSED with
// output recombination. One wave per (b,i). Phases:
//  0. Stage the block's 4 X rows (2 KB) into LDS — replaces R9's 512
//     __shfl broadcasts per wave in the tail with 128 ds_read_b128
//     broadcast reads (uniform address, conflict-free): 4x less DS-unit
//     occupancy (the DS unit is a single shared per-CU resource also used
//     by the butterfly).
//  1. Prelude: 16 ar/ai coefficient pairs per lane, in registers.
//  2. Stream: 4 m-slices of L (32 KB/wave) with a 2-deep burst pipeline.
//  3. Butterfly reduce leaves rowR/rowI[m] in ALL lanes (no global
//     round-trip).
//  4. Tail: the 4 waves split the recombine GEMM by weight-plane m==wave
//     (weights stay L2-resident, traffic hidden under other waves'
//     streaming), exchange 8 KB u/v panels via LDS, emit out rows.
// Arithmetic values and accumulation order identical to R9.
// ---------------------------------------------------------------------------
__global__ __launch_bounds__(256)
void k_stream_out(const float* __restrict__ Lr, const float* __restrict__ Li,
                  const float* __restrict__ sRi, const float* __restrict__ sIi,
                  const float* __restrict__ sRj, const float* __restrict__ sIj,
                  const float* __restrict__ cmax, const float* __restrict__ cinv,
                  const float* __restrict__ abr, const float* __restrict__ abi,
                  const float* __restrict__ par_, const float* __restrict__ pai_,
                  const float* __restrict__ Xr, const float* __restrict__ Xi,
                  const float* __restrict__ wr, const float* __restrict__ wi,
                  float* __restrict__ out) {
    __shared__ __align__(16) float lxr[4][64];   // block's 4 X rows (c-major)
    __shared__ __align__(16) float lxi[4][64];
    __shared__ float luR[4][4][64];   // [m-plane][row-in-block][o]
    __shared__ float luI[4][4][64];
    const int tid  = threadIdx.x;
    const int lane = tid & 63;
    const int wave = tid >> 6;
    const int wid  = (blockIdx.x << 2) + wave;  // b*N + i (blocks never straddle b)
    const int b    = wid >> 10;
    const int i    = wid & 1023;
    const int row0 = blockIdx.x << 2;

    // Phase 0: stage X rows. One float per thread per array (coalesced 1 KB).
    lxr[tid >> 6][tid & 63] = Xr[((size_t)row0 << 6) + tid];
    lxi[tid >> 6][tid & 63] = Xi[((size_t)row0 << 6) + tid];

    const float br = abr[0], bi = abi[0], par = par_[0], pai = pai_[0];
    const float sri = sRi[wid], sii = sIi[wid];

    const float4* SRJ = (const float4*)(sRj + (b << 10));
    const float4* SIJ = (const float4*)(sIj + (b << 10));
    const float4* CMX = (const float4*)(cmax + (b << 10));
    const float4* CIV = (const float4*)(cinv + (b << 10));

    // Phase 1: 16 ar/ai pairs per lane, j = 4*(t*64+lane)+e.
    float arv[16], aiv[16];
#pragma unroll
    for (int t = 0; t < 4; ++t) {
        const int j4 = (t << 6) + lane;
        const float4 vr = SRJ[j4];
        const float4 vi = SIJ[j4];
        const float4 vm = CMX[j4];
        const float4 vs = CIV[j4];
        attn_coef(vr.x, vi.x, vm.x, vs.x, sri, sii, br, bi, par, pai,
                  arv[(t << 2) + 0], aiv[(t << 2) + 0]);
        attn_coef(vr.y, vi.y, vm.y, vs.y, sri, sii, br, bi, par, pai,
                  arv[(t << 2) + 1], aiv[(t << 2) + 1]);
        attn_coef(vr.z, vi.z, vm.z, vs.z, sri, sii, br, bi, par, pai,
                  arv[(t << 2) + 2], aiv[(t << 2) + 2]);
        attn_coef(vr.w, vi.w, vm.w, vs.w, sri, sii, br, bi, par, pai,
                  arv[(t << 2) + 3], aiv[(t << 2) + 3]);
    }

    // Phase 2: stream L[b,m,i,:], m=0..3; float4-index stride per m = 1<<18.
    const size_t base = ((size_t)b << 22) + ((size_t)i << 10);
    const nfloat4* LR = (const nfloat4*)(Lr + base);
    const nfloat4* LI = (const nfloat4*)(Li + base);

    float accR[4] = {0.f, 0.f, 0.f, 0.f};
    float accI[4] = {0.f, 0.f, 0.f, 0.f};
    nfloat4 rA[4], qA[4], rB[4], qB[4];
    LOAD_BURST(0, rA, qA);            // m0 -> A
    LOAD_BURST(1, rB, qB);            // m1 -> B  (2 bursts in flight)
    FMA_BURST(0, rA, qA);             // consume m0
    LOAD_BURST(2, rA, qA);            // m2 -> A  (keeps >=1 burst in flight)
    FMA_BURST(1, rB, qB);             // consume m1
    LOAD_BURST(3, rB, qB);            // m3 -> B
    FMA_BURST(2, rA, qA);             // consume m2
    FMA_BURST(3, rB, qB);             // consume m3

    // Phase 3: butterfly — ALL lanes end up with the full row sums.
#pragma unroll
    for (int m = 0; m < 4; ++m) {
#pragma unroll
        for (int s = 32; s > 0; s >>= 1) {
            accR[m] += __shfl_xor(accR[m], s, 64);
            accI[m] += __shfl_xor(accI[m], s, 64);
        }
    }

    // Phase 4: output recombination, split by weight-plane m == wave.
    __syncthreads();   // lxr/lxi stage visible (writes happened long ago)
    float u[4] = {0.f, 0.f, 0.f, 0.f};
    float v[4] = {0.f, 0.f, 0.f, 0.f};
#pragma unroll 4
    for (int c4 = 0; c4 < 16; ++c4) {
        const int cb = c4 << 2;
        // 8 coalesced weight loads (L2-resident 128 KB weight block).
        const float wr0 = wr[(((wave << 6) + cb + 0) << 6) + lane];
        const float wr1 = wr[(((wave << 6) + cb + 1) << 6) + lane];
        const float wr2 = wr[(((wave << 6) + cb + 2) << 6) + lane];
        const float wr3 = wr[(((wave << 6) + cb + 3) << 6) + lane];
        const float wi0 = wi[(((wave << 6) + cb + 0) << 6) + lane];
        const float wi1 = wi[(((wave << 6) + cb + 1) << 6) + lane];
        const float wi2 = wi[(((wave << 6) + cb + 2) << 6) + lane];
        const float wi3 = wi[(((wave << 6) + cb + 3) << 6) + lane];
#pragma unroll
        for (int r = 0; r < 4; ++r) {
            // Broadcast ds_read_b128 (uniform address -> conflict-free).
            const float4 x4 = ((const float4*)&lxr[r][0])[c4];
            const float4 y4 = ((const float4*)&lxi[r][0])[c4];
            u[r] += x4.x * wr0;  u[r] += x4.y * wr1;
            u[r] += x4.z * wr2;  u[r] += x4.w * wr3;
            v[r] += y4.x * wi0;  v[r] += y4.y * wi1;
            v[r] += y4.z * wi2;  v[r] += y4.w * wi3;
        }
    }
#pragma unroll
    for (int r = 0; r < 4; ++r) {
        luR[wave][r][lane] = u[r];
        luI[wave][r][lane] = v[r];
    }
    __syncthreads();
    float re = 0.f, im = 0.f;
#pragma unroll
    for (int m = 0; m < 4; ++m) {
        const float um = luR[m][wave][lane];
        const float vm = luI[m][wave][lane];
        re += accR[m] * um - accI[m] * vm;
        im += accI[m] * um + accR[m] * vm;
    }
    out[(size_t)wid * 64 + lane] = re;
    out[524288 + (size_t)wid * 64 + lane] = im;  // imag block
}

extern "C" void kernel_launch(void* const* d_in, const int* in_sizes, int n_in,
                              void* d_out, int out_size, void* d_ws, size_t ws_size,
                              hipStream_t stream) {
    const float* Xr  = (const float*)d_in[0];
    const float* Xi  = (const float*)d_in[1];
    const float* Lr  = (const float*)d_in[2];
    const float* Li  = (const float*)d_in[3];
    const float* wr  = (const float*)d_in[4];
    const float* wi  = (const float*)d_in[5];
    const float* awr = (const float*)d_in[6];
    const float* awi = (const float*)d_in[7];
    const float* abr = (const float*)d_in[8];
    const float* abi = (const float*)d_in[9];
    const float* par = (const float*)d_in[10];
    const float* pai = (const float*)d_in[11];
    float* out = (float*)d_out;

    // Workspace layout (floats):
    // sRi[8192] sIi[8192] sRj[8192] sIj[8192] cmax[8192] cinv[8192] = 192 KB
    float* ws   = (float*)d_ws;
    float* sRi  = ws;
    float* sIi  = ws + 8192;
    float* sRj  = ws + 16384;
    float* sIj  = ws + 24576;
    float* cmax = ws + 32768;
    float* cinv = ws + 40960;

    k_scores    <<<dim3(2048), dim3(256), 0, stream>>>(Xr, Xi, awr, awi, sRi, sIi, sRj, sIj);
    k_softmax   <<<dim3(2048), dim3(256), 0, stream>>>(sRi, sIi, sRj, sIj, cmax, cinv,
                                                       abr, abi, par, pai);
    k_stream_out<<<dim3(2048), dim3(256), 0, stream>>>(Lr, Li, sRi, sIi, sRj, sIj, cmax, cinv,
                                                       abr, abi, par, pai,
                                                       Xr, Xi, wr, wi, out);
}